// Round 19
// baseline (132.670 us; speedup 1.0000x reference)
//
#include <hip/hip_runtime.h>

#define DEV static __device__ __forceinline__

using bf16x8 = __attribute__((ext_vector_type(8))) short;
using f32x4  = __attribute__((ext_vector_type(4))) float;
using f32x16 = __attribute__((ext_vector_type(16))) float;

#if __has_builtin(__builtin_amdgcn_exp2f)
#define EXP2(x) __builtin_amdgcn_exp2f(x)
#else
#define EXP2(x) exp2f(x)
#endif

DEV unsigned short f2bf(float f) {
  union { float f; unsigned u; } v; v.f = f;
  return (unsigned short)((v.u + 0x7fffu + ((v.u >> 16) & 1u)) >> 16);
}
DEV float bf2f(unsigned short b) {
  union { unsigned u; float f; } v; v.u = ((unsigned)b) << 16;
  return v.f;
}
// single-instruction packed fp32->bf16 (RNE)
DEV unsigned cvtpk(float lo, float hi) {
  unsigned r;
  asm("v_cvt_pk_bf16_f32 %0, %1, %2" : "=v"(r) : "v"(lo), "v"(hi));
  return r;
}
// swap: a_new=[a_lo,b_lo], b_new=[a_hi,b_hi] across lane halves
DEV void pl32swap(unsigned &a, unsigned &b) {
  asm("v_permlane32_swap_b32 %0, %1" : "+v"(a), "+v"(b));
}
DEV bf16x8 mk8(unsigned a, unsigned b, unsigned c, unsigned d) {
  union { unsigned u[4]; bf16x8 v; } t;
  t.u[0] = a; t.u[1] = b; t.u[2] = c; t.u[3] = d;
  return t.v;
}
DEV f32x4 mfma16(bf16x8 a, bf16x8 b, f32x4 c) {
  return __builtin_amdgcn_mfma_f32_16x16x32_bf16(a, b, c, 0, 0, 0);
}
DEV f32x16 mfma32(bf16x8 a, bf16x8 b, f32x16 c) {
  return __builtin_amdgcn_mfma_f32_32x32x16_bf16(a, b, c, 0, 0, 0);
}
DEV f32x16 zero16() {
  f32x16 z;
#pragma unroll
  for (int i = 0; i < 16; ++i) z[i] = 0.f;
  return z;
}

typedef const __attribute__((address_space(1))) unsigned int* gas1;
typedef __attribute__((address_space(3))) unsigned int* las3;
DEV void gl16(const void* g, void* l) {
  __builtin_amdgcn_global_load_lds((gas1)g, (las3)l, 16, 0, 0);
}

// ---------------------------------------------------------------------------
// fp32 -> bf16 pre-convert: x1(4M) x2(4M) Wq Wk Wv Wp (1M each) -> 12M ushort.
// ---------------------------------------------------------------------------
__global__ __launch_bounds__(256, 8)
void conv_bf16(const float* __restrict__ x1, const float* __restrict__ x2,
               const float* __restrict__ Wq, const float* __restrict__ Wk,
               const float* __restrict__ Wv, const float* __restrict__ Wp,
               unsigned short* __restrict__ o)
{
  size_t e = ((size_t)blockIdx.x * 256 + threadIdx.x) * 8;
  const float* s; size_t off;
  if (e < 4194304u)       { s = x1; off = e; }
  else if (e < 8388608u)  { s = x2; off = e - 4194304u; }
  else if (e < 9437184u)  { s = Wq; off = e - 8388608u; }
  else if (e < 10485760u) { s = Wk; off = e - 9437184u; }
  else if (e < 11534336u) { s = Wv; off = e - 10485760u; }
  else                    { s = Wp; off = e - 11534336u; }
  const float4* p = reinterpret_cast<const float4*>(s + off);
  float4 a = p[0], b = p[1];
  int4 r;
  r.x = (int)cvtpk(a.x, a.y); r.y = (int)cvtpk(a.z, a.w);
  r.z = (int)cvtpk(b.x, b.y); r.w = (int)cvtpk(b.z, b.w);
  *reinterpret_cast<int4*>(o + e) = r;
}

// ---------------------------------------------------------------------------
// Fused QKV GEMM (m97 structure) + fused per-head LayerNorm epilogue.
// XCD-aware tile swizzle. 3 z-slices.
// ---------------------------------------------------------------------------
__global__ __launch_bounds__(256, 4)
void gemm_qkv_bf(const unsigned short* __restrict__ xb,
                 const float* __restrict__ lg, const float* __restrict__ lb,
                 unsigned short* __restrict__ qb, unsigned short* __restrict__ kb,
                 unsigned short* __restrict__ vtb)
{
  __shared__ short As[128 * 64];
  __shared__ short Bs[128 * 64];
  const int tid = threadIdx.x;
  const int l = tid & 63, w = tid >> 6;
  const int wr = w >> 1, wc = w & 1;
  const int z = blockIdx.z;
  const unsigned short* A = (z == 0) ? xb : (xb + 4194304);
  const unsigned short* W = xb + 8388608 + (size_t)z * 1048576;
  const int id = blockIdx.x + (blockIdx.y << 3);
  const int tl = ((id & 7) << 5) | (id >> 3);
  const int bx = tl & 7, by = tl >> 3;
  const int brow = by * 128, bcol = bx * 128;

  const f32x4 zero = {0.f, 0.f, 0.f, 0.f};
  f32x4 acc[4][4];
#pragma unroll
  for (int mi = 0; mi < 4; ++mi)
#pragma unroll
    for (int ni = 0; ni < 4; ++ni) acc[mi][ni] = zero;

  const int srow = w * 32 + (l >> 3);
  const int scol = (l & 7) * 8;

  for (int kt = 0; kt < 16; ++kt) {
    const unsigned short* ga = A + (size_t)(brow + srow) * 1024 + kt * 64 + scol;
    const unsigned short* gb = W + (size_t)(bcol + srow) * 1024 + kt * 64 + scol;
#pragma unroll
    for (int i = 0; i < 4; ++i) {
      gl16(ga + (size_t)i * 8 * 1024, &As[(w * 32 + i * 8) * 64]);
      gl16(gb + (size_t)i * 8 * 1024, &Bs[(w * 32 + i * 8) * 64]);
    }
    __syncthreads();
#pragma unroll
    for (int kk = 0; kk < 2; ++kk) {
      const int k0 = kk * 32 + ((l >> 4) << 3);
      bf16x8 af[4], bfr[4];
#pragma unroll
      for (int mi = 0; mi < 4; ++mi)
        af[mi] = *reinterpret_cast<const bf16x8*>(
            &As[((wr << 6) + (mi << 4) + (l & 15)) * 64 + k0]);
#pragma unroll
      for (int ni = 0; ni < 4; ++ni)
        bfr[ni] = *reinterpret_cast<const bf16x8*>(
            &Bs[((wc << 6) + (ni << 4) + (l & 15)) * 64 + k0]);
#pragma unroll
      for (int mi = 0; mi < 4; ++mi)
#pragma unroll
        for (int ni = 0; ni < 4; ++ni)
          acc[mi][ni] = mfma16(af[mi], bfr[ni], acc[mi][ni]);
    }
    __syncthreads();
  }

  if (z < 2) {
    unsigned short* dst = (z == 0) ? qb : kb;
    const float scl = (z == 0) ? 0.18033688011112042f : 1.0f; // 0.125*log2(e)
    const int h = bx * 2 + wc;
    float gw4[4], bw4[4];
#pragma unroll
    for (int ni = 0; ni < 4; ++ni) {
      gw4[ni] = lg[ni * 16 + (l & 15)] * scl;
      bw4[ni] = lb[ni * 16 + (l & 15)] * scl;
    }
#pragma unroll
    for (int mi = 0; mi < 4; ++mi) {
      float ylo[4];
#pragma unroll
      for (int r = 0; r < 4; ++r) {
        float v0 = acc[mi][0][r], v1 = acc[mi][1][r];
        float v2 = acc[mi][2][r], v3 = acc[mi][3][r];
        float s  = (v0 + v1) + (v2 + v3);
        float s2 = (v0 * v0 + v1 * v1) + (v2 * v2 + v3 * v3);
#pragma unroll
        for (int off = 1; off < 16; off <<= 1) {
          s  += __shfl_xor(s, off);
          s2 += __shfl_xor(s2, off);
        }
        float mean = s * (1.f / 64.f);
        float var  = s2 * (1.f / 64.f) - mean * mean;
        float rstd = rsqrtf(var + 1e-5f);
        float y[4];
        y[0] = (v0 - mean) * rstd * gw4[0] + bw4[0];
        y[1] = (v1 - mean) * rstd * gw4[1] + bw4[1];
        y[2] = (v2 - mean) * rstd * gw4[2] + bw4[2];
        y[3] = (v3 - mean) * rstd * gw4[3] + bw4[3];
        if (!(r & 1)) {
          ylo[0] = y[0]; ylo[1] = y[1]; ylo[2] = y[2]; ylo[3] = y[3];
        } else {
          int rowg0 = brow + (wr << 6) + (mi << 4) + ((l >> 4) << 2) + r - 1;
          int b = rowg0 >> 11, n = rowg0 & 2047;
          unsigned short* base =
              dst + (((size_t)(b * 16 + h) << 11) + n) * 64 + (l & 15);
#pragma unroll
          for (int ni = 0; ni < 4; ++ni) {
            unsigned u = cvtpk(ylo[ni], y[ni]);
            base[ni * 16]      = (unsigned short)(u & 0xffffu);
            base[ni * 16 + 64] = (unsigned short)(u >> 16);
          }
        }
      }
    }
  } else {
    const int bb = brow >> 11;
    const int nblk = brow & 2047;
#pragma unroll
    for (int mi = 0; mi < 4; ++mi)
#pragma unroll
      for (int ni = 0; ni < 4; ++ni) {
        int n0 = nblk + (wr << 6) + (mi << 4) + ((l >> 4) << 2);
        int colg = bcol + (wc << 6) + (ni << 4) + (l & 15);
        int h = colg >> 6, d = colg & 63;
        unsigned u0 = cvtpk(acc[mi][ni][0], acc[mi][ni][1]);
        unsigned u1 = cvtpk(acc[mi][ni][2], acc[mi][ni][3]);
        int2 u; u.x = (int)u0; u.y = (int)u1;
        *reinterpret_cast<int2*>(
            &vtb[((size_t)(bb * 16 + h) * 64 + d) * 2048 + n0]) = u;
      }
  }
}

// ---------------------------------------------------------------------------
// Flash attention, SPLIT-KV x4, 64-q-rows-per-wave (round-16/18 proven body;
// only the split factor changes).  Grid (16,32,4) = 2048 blocks -> 5 resident
// blocks/CU (LDS-capped) instead of the grid-limited 4.  8 KV tiles/block.
// K/V staged via global_load_lds (linear dest + inverse-swizzled source).
// ---------------------------------------------------------------------------
__global__ __launch_bounds__(128, 2)
void attn_fwd(const unsigned short* __restrict__ Q,
              const unsigned short* __restrict__ K,
              const unsigned short* __restrict__ Vt,
              unsigned short* __restrict__ pnum,
              float* __restrict__ plsum)
{
  __shared__ short Ks[2][64 * 64];
  __shared__ short Vs[2][64 * 64];
  const int tid = threadIdx.x, w = tid >> 6, l = tid & 63;
  const int lo5 = l & 31, hi = l >> 5;
  const int bh = blockIdx.y;
  const int half = blockIdx.z;              // 0..3 (quarter of KV)
  const int tbase = half * 8;               // 8 tiles of 64 j each
  const int qbase = blockIdx.x * 128 + w * 64;
  const unsigned short* Qg = Q + ((size_t)bh * 2048 + qbase) * 64;
  const unsigned short* Kg = K + (size_t)bh * 2048 * 64;
  const unsigned short* Vg = Vt + (size_t)bh * 64 * 2048;

  bf16x8 qfA[4], qfB[4];
#pragma unroll
  for (int ks = 0; ks < 4; ++ks) {
    qfA[ks] = *reinterpret_cast<const bf16x8*>(Qg + lo5 * 64 + ks * 16 + hi * 8);
    qfB[ks] = *reinterpret_cast<const bf16x8*>(Qg + (32 + lo5) * 64 + ks * 16 + hi * 8);
  }
  const bf16x8 ones = mk8(0x3F803F80u, 0x3F803F80u, 0x3F803F80u, 0x3F803F80u);

  f32x16 oc0a = zero16(), oc1a = zero16(), lsa = zero16();
  f32x16 oc0b = zero16(), oc1b = zero16(), lsb = zero16();

  // staging geometry: thread covers rows srow+16g (g=0..3), 16B slot tid&7.
  // gl16: LDS dest linear (wave-uniform base + lane*16); global source column
  // carries the INVERSE swizzle (XOR is an involution).
  const int srow = tid >> 3;                          // 0..15
  const int scs = (((tid & 7) ^ (srow & 7)) * 8);     // pre-swizzled src col

  const unsigned short* kp = Kg + (size_t)tbase * 4096 + srow * 64 + scs;
  const unsigned short* vp = Vg + (size_t)tbase * 64 + (size_t)srow * 2048 + scs;
  short* kd0 = &Ks[0][w * 512]; short* kd1 = &Ks[1][w * 512];
  short* vd0 = &Vs[0][w * 512]; short* vd1 = &Vs[1][w * 512];

#define STAGEKV(KD, VD)                                                        \
  gl16(kp,         (KD));                                                      \
  gl16(kp + 1024,  (KD) + 1024);                                               \
  gl16(kp + 2048,  (KD) + 2048);                                               \
  gl16(kp + 3072,  (KD) + 3072);                                               \
  gl16(vp,         (VD));                                                      \
  gl16(vp + 32768, (VD) + 1024);                                               \
  gl16(vp + 65536, (VD) + 2048);                                               \
  gl16(vp + 98304, (VD) + 3072);                                               \
  kp += 4096; vp += 64

  STAGEKV(kd0, vd0);          // prologue: tile tbase -> buffer 0
  __syncthreads();

  for (int it = 0; it < 8; ++it) {
    const int cur = it & 1;
    const short* Kc = Ks[cur];
    const short* Vc = Vs[cur];

    if (it < 7) {             // stage next tile into the other buffer (async)
      if (cur == 0) { STAGEKV(kd1, vd1); }
      else          { STAGEKV(kd0, vd0); }
    }

    // QK^T (swapped): each K fragment feeds BOTH q-tiles
    f32x16 s0a = zero16(), s1a = zero16(), s0b = zero16(), s1b = zero16();
    __builtin_amdgcn_s_setprio(1);
#pragma unroll
    for (int ks = 0; ks < 4; ++ks) {
      const int colc = (16 * ks + 8 * hi) ^ ((lo5 & 7) << 3);
      bf16x8 k0 = *reinterpret_cast<const bf16x8*>(&Kc[(lo5 << 6) + colc]);
      bf16x8 k1 = *reinterpret_cast<const bf16x8*>(&Kc[((32 + lo5) << 6) + colc]);
      s0a = mfma32(k0, qfA[ks], s0a);
      s1a = mfma32(k1, qfA[ks], s1a);
      s0b = mfma32(k0, qfB[ks], s0b);
      s1b = mfma32(k1, qfB[ks], s1b);
    }
    __builtin_amdgcn_s_setprio(0);

    // static softmax + PV; V fragments shared by both q-tiles
    auto pvpair = [&](const f32x16& sa, const f32x16& sb, int jbase) {
      float pA[16], pB[16];
#pragma unroll
      for (int r = 0; r < 16; ++r) { pA[r] = EXP2(sa[r]); pB[r] = EXP2(sb[r]); }
#pragma unroll
      for (int f = 0; f < 2; ++f) {
        unsigned xA  = cvtpk(pA[8 * f + 0], pA[8 * f + 1]);
        unsigned zA  = cvtpk(pA[8 * f + 2], pA[8 * f + 3]);
        unsigned yA  = cvtpk(pA[8 * f + 4], pA[8 * f + 5]);
        unsigned wA  = cvtpk(pA[8 * f + 6], pA[8 * f + 7]);
        pl32swap(xA, yA);
        pl32swap(zA, wA);
        bf16x8 paA = mk8(xA, zA, yA, wA);
        unsigned xB  = cvtpk(pB[8 * f + 0], pB[8 * f + 1]);
        unsigned zB  = cvtpk(pB[8 * f + 2], pB[8 * f + 3]);
        unsigned yB  = cvtpk(pB[8 * f + 4], pB[8 * f + 5]);
        unsigned wB  = cvtpk(pB[8 * f + 6], pB[8 * f + 7]);
        pl32swap(xB, yB);
        pl32swap(zB, wB);
        bf16x8 paB = mk8(xB, zB, yB, wB);
        const int colc = (jbase + 16 * f + 8 * hi);
        bf16x8 v0 = *reinterpret_cast<const bf16x8*>(
            &Vc[(lo5 << 6) + (colc ^ ((lo5 & 7) << 3))]);
        bf16x8 v1 = *reinterpret_cast<const bf16x8*>(
            &Vc[((32 + lo5) << 6) + (colc ^ ((lo5 & 7) << 3))]);
        __builtin_amdgcn_s_setprio(1);
        oc0a = mfma32(paA, v0, oc0a);
        oc1a = mfma32(paA, v1, oc1a);
        lsa  = mfma32(paA, ones, lsa);
        oc0b = mfma32(paB, v0, oc0b);
        oc1b = mfma32(paB, v1, oc1b);
        lsb  = mfma32(paB, ones, lsb);
        __builtin_amdgcn_s_setprio(0);
      }
    };
    pvpair(s0a, s0b, 0);
    pvpair(s1a, s1b, 32);

    __syncthreads();   // drains this iter's gl16s (vmcnt 0 at barrier) + swap
  }
#undef STAGEKV

  // epilogue: write raw bf16 partial numerators + fp32 partial row-sums.
  unsigned short* Pn = pnum + ((size_t)(half * 32 + bh) * 2048 + qbase) * 64;
#pragma unroll
  for (int r = 0; r < 16; ++r) {
    int qrow = (r & 3) + 8 * (r >> 2) + 4 * hi;
    Pn[qrow * 64 + lo5]             = f2bf(oc0a[r]);
    Pn[qrow * 64 + 32 + lo5]        = f2bf(oc1a[r]);
    Pn[(32 + qrow) * 64 + lo5]      = f2bf(oc0b[r]);
    Pn[(32 + qrow) * 64 + 32 + lo5] = f2bf(oc1b[r]);
  }
  if (lo5 == 0) {
    float* Pl = plsum + (size_t)(half * 32 + bh) * 2048 + qbase;
#pragma unroll
    for (int r = 0; r < 16; ++r) {
      int qrow = (r & 3) + 8 * (r >> 2) + 4 * hi;
      Pl[qrow]      = lsa[r];
      Pl[32 + qrow] = lsb[r];
    }
  }
}

// ---------------------------------------------------------------------------
// Combine the four KV quarters: out = sum(n_h) / sum(ls_h), obuf [B,N,H*64].
// ---------------------------------------------------------------------------
__global__ __launch_bounds__(256, 8)
void attn_combine(const unsigned short* __restrict__ pnum,
                  const float* __restrict__ plsum,
                  unsigned short* __restrict__ obuf)
{
  const int t = blockIdx.x * 256 + threadIdx.x;   // 0..524287
  const int bh = t >> 14;
  const int rem = t & 16383;
  const int q = rem >> 3, dblk = rem & 7;
  const size_t i0 = (((size_t)bh * 2048) + q) * 64 + dblk * 8;
  const size_t STR = (size_t)32 * 2048 * 64;      // per-quarter stride (ushorts)
  float acc[8];
#pragma unroll
  for (int e = 0; e < 8; ++e) acc[e] = 0.f;
#pragma unroll
  for (int h = 0; h < 4; ++h) {
    ushort4 a0 = *reinterpret_cast<const ushort4*>(pnum + i0 + h * STR);
    ushort4 a1 = *reinterpret_cast<const ushort4*>(pnum + i0 + h * STR + 4);
    acc[0] += bf2f(a0.x); acc[1] += bf2f(a0.y);
    acc[2] += bf2f(a0.z); acc[3] += bf2f(a0.w);
    acc[4] += bf2f(a1.x); acc[5] += bf2f(a1.y);
    acc[6] += bf2f(a1.z); acc[7] += bf2f(a1.w);
  }
  float ls = (plsum[bh * 2048 + q]           + plsum[65536 + bh * 2048 + q]) +
             (plsum[131072 + bh * 2048 + q]  + plsum[196608 + bh * 2048 + q]);
  float inv = 1.f / ls;
  ushort4 o0, o1;
  o0.x = f2bf(acc[0] * inv); o0.y = f2bf(acc[1] * inv);
  o0.z = f2bf(acc[2] * inv); o0.w = f2bf(acc[3] * inv);
  o1.x = f2bf(acc[4] * inv); o1.y = f2bf(acc[5] * inv);
  o1.z = f2bf(acc[6] * inv); o1.w = f2bf(acc[7] * inv);
  unsigned short* dst = obuf + ((size_t)(bh >> 4) * 2048 + q) * 1024 +
                        (bh & 15) * 64 + dblk * 8;
  *reinterpret_cast<ushort4*>(dst) = o0;
  *reinterpret_cast<ushort4*>(dst + 4) = o1;
}

// ---------------------------------------------------------------------------
// Output projection (m97 structure): out = Ocat @ Wp^T + bp, fp32 out.
// XCD-aware tile swizzle.
// ---------------------------------------------------------------------------
__global__ __launch_bounds__(256, 4)
void gemm_out_bf(const unsigned short* __restrict__ ob,
                 const unsigned short* __restrict__ wpb,
                 const float* __restrict__ bp, float* __restrict__ out)
{
  __shared__ short As[128 * 64];
  __shared__ short Bs[128 * 64];
  const int tid = threadIdx.x;
  const int l = tid & 63, w = tid >> 6;
  const int wr = w >> 1, wc = w & 1;
  const int id = blockIdx.x + (blockIdx.y << 3);
  const int tl = ((id & 7) << 5) | (id >> 3);
  const int brow = (tl >> 3) * 128, bcol = (tl & 7) * 128;

  const f32x4 zero = {0.f, 0.f, 0.f, 0.f};
  f32x4 acc[4][4];
#pragma unroll
  for (int mi = 0; mi < 4; ++mi)
#pragma unroll
    for (int ni = 0; ni < 4; ++ni) acc[mi][ni] = zero;

  const int srow = w * 32 + (l >> 3);
  const int scol = (l & 7) * 8;

  for (int kt = 0; kt < 16; ++kt) {
    const unsigned short* ga = ob + (size_t)(brow + srow) * 1024 + kt * 64 + scol;
    const unsigned short* gb = wpb + (size_t)(bcol + srow) * 1024 + kt * 64 + scol;
#pragma unroll
    for (int i = 0; i < 4; ++i) {
      gl16(ga + (size_t)i * 8 * 1024, &As[(w * 32 + i * 8) * 64]);
      gl16(gb + (size_t)i * 8 * 1024, &Bs[(w * 32 + i * 8) * 64]);
    }
    __syncthreads();
#pragma unroll
    for (int kk = 0; kk < 2; ++kk) {
      const int k0 = kk * 32 + ((l >> 4) << 3);
      bf16x8 af[4], bfr[4];
#pragma unroll
      for (int mi = 0; mi < 4; ++mi)
        af[mi] = *reinterpret_cast<const bf16x8*>(
            &As[((wr << 6) + (mi << 4) + (l & 15)) * 64 + k0]);
#pragma unroll
      for (int ni = 0; ni < 4; ++ni)
        bfr[ni] = *reinterpret_cast<const bf16x8*>(
            &Bs[((wc << 6) + (ni << 4) + (l & 15)) * 64 + k0]);
#pragma unroll
      for (int mi = 0; mi < 4; ++mi)
#pragma unroll
        for (int ni = 0; ni < 4; ++ni)
          acc[mi][ni] = mfma16(af[mi], bfr[ni], acc[mi][ni]);
    }
    __syncthreads();
  }

  float bias[4];
#pragma unroll
  for (int ni = 0; ni < 4; ++ni)
    bias[ni] = bp[bcol + (wc << 6) + (ni << 4) + (l & 15)];
#pragma unroll
  for (int mi = 0; mi < 4; ++mi)
#pragma unroll
    for (int ni = 0; ni < 4; ++ni)
#pragma unroll
      for (int r = 0; r < 4; ++r) {
        int rowg = brow + (wr << 6) + (mi << 4) + ((l >> 4) << 2) + r;
        int colg = bcol + (wc << 6) + (ni << 4) + (l & 15);
        out[(size_t)rowg * 1024 + colg] = acc[mi][ni][r] + bias[ni];
      }
}

// ---------------------------------------------------------------------------
extern "C" void kernel_launch(void* const* d_in, const int* in_sizes, int n_in,
                              void* d_out, int out_size, void* d_ws, size_t ws_size,
                              hipStream_t stream)
{
  const float* x1 = (const float*)d_in[0];
  const float* x2 = (const float*)d_in[1];
  const float* Wq = (const float*)d_in[2];
  const float* Wk = (const float*)d_in[3];
  const float* Wv = (const float*)d_in[4];
  const float* Wp = (const float*)d_in[5];
  const float* bp = (const float*)d_in[6];
  const float* lg = (const float*)d_in[7];
  const float* lb = (const float*)d_in[8];

  char* wsb = (char*)d_ws;
  unsigned short* xb   = (unsigned short*)wsb;              // 24 MiB (12M ushort)
  unsigned short* qb   = (unsigned short*)(wsb + 25165824); // 8 MiB
  unsigned short* kb   = qb + 4194304;                      // 8 MiB
  unsigned short* vtb  = kb + 4194304;                      // 8 MiB (V^T)
  unsigned short* obuf = vtb + 4194304;                     // 8 MiB
  unsigned short* pnum = obuf + 4194304;                    // 32 MiB (4 quarters)
  // plsum (1 MiB) overlays the x1-bf16 region (dead after gemm_qkv).
  float* plsum = (float*)wsb;
  float* out = (float*)d_out;

  conv_bf16<<<6144, 256, 0, stream>>>(x1, x2, Wq, Wk, Wv, Wp, xb);
  gemm_qkv_bf<<<dim3(8, 32, 3), 256, 0, stream>>>(xb, lg, lb, qb, kb, vtb);
  attn_fwd<<<dim3(16, 32, 4), 128, 0, stream>>>(qb, kb, vtb, pnum, plsum);
  attn_combine<<<2048, 256, 0, stream>>>(pnum, plsum, obuf);
  gemm_out_bf<<<dim3(8, 32), 256, 0, stream>>>(obuf,
      xb + 11534336, bp, out);
}

// Round 20
// 124.247 us; speedup vs baseline: 1.0678x; 1.0678x over previous
//
#include <hip/hip_runtime.h>

#define DEV static __device__ __forceinline__

using bf16x8 = __attribute__((ext_vector_type(8))) short;
using f32x4  = __attribute__((ext_vector_type(4))) float;
using f32x16 = __attribute__((ext_vector_type(16))) float;

#if __has_builtin(__builtin_amdgcn_exp2f)
#define EXP2(x) __builtin_amdgcn_exp2f(x)
#else
#define EXP2(x) exp2f(x)
#endif

DEV unsigned short f2bf(float f) {
  union { float f; unsigned u; } v; v.f = f;
  return (unsigned short)((v.u + 0x7fffu + ((v.u >> 16) & 1u)) >> 16);
}
DEV float bf2f(unsigned short b) {
  union { unsigned u; float f; } v; v.u = ((unsigned)b) << 16;
  return v.f;
}
// single-instruction packed fp32->bf16 (RNE)
DEV unsigned cvtpk(float lo, float hi) {
  unsigned r;
  asm("v_cvt_pk_bf16_f32 %0, %1, %2" : "=v"(r) : "v"(lo), "v"(hi));
  return r;
}
// swap: a_new=[a_lo,b_lo], b_new=[a_hi,b_hi] across lane halves
DEV void pl32swap(unsigned &a, unsigned &b) {
  asm("v_permlane32_swap_b32 %0, %1" : "+v"(a), "+v"(b));
}
DEV bf16x8 mk8(unsigned a, unsigned b, unsigned c, unsigned d) {
  union { unsigned u[4]; bf16x8 v; } t;
  t.u[0] = a; t.u[1] = b; t.u[2] = c; t.u[3] = d;
  return t.v;
}
DEV f32x4 mfma16(bf16x8 a, bf16x8 b, f32x4 c) {
  return __builtin_amdgcn_mfma_f32_16x16x32_bf16(a, b, c, 0, 0, 0);
}
DEV f32x16 mfma32(bf16x8 a, bf16x8 b, f32x16 c) {
  return __builtin_amdgcn_mfma_f32_32x32x16_bf16(a, b, c, 0, 0, 0);
}
DEV f32x16 zero16() {
  f32x16 z;
#pragma unroll
  for (int i = 0; i < 16; ++i) z[i] = 0.f;
  return z;
}

typedef const __attribute__((address_space(1))) unsigned int* gas1;
typedef __attribute__((address_space(3))) unsigned int* las3;
DEV void gl16(const void* g, void* l) {
  __builtin_amdgcn_global_load_lds((gas1)g, (las3)l, 16, 0, 0);
}

// ---------------------------------------------------------------------------
// fp32 -> bf16 pre-convert: x1(4M) x2(4M) Wq Wk Wv Wp (1M each) -> 12M ushort.
// ---------------------------------------------------------------------------
__global__ __launch_bounds__(256, 8)
void conv_bf16(const float* __restrict__ x1, const float* __restrict__ x2,
               const float* __restrict__ Wq, const float* __restrict__ Wk,
               const float* __restrict__ Wv, const float* __restrict__ Wp,
               unsigned short* __restrict__ o)
{
  size_t e = ((size_t)blockIdx.x * 256 + threadIdx.x) * 8;
  const float* s; size_t off;
  if (e < 4194304u)       { s = x1; off = e; }
  else if (e < 8388608u)  { s = x2; off = e - 4194304u; }
  else if (e < 9437184u)  { s = Wq; off = e - 8388608u; }
  else if (e < 10485760u) { s = Wk; off = e - 9437184u; }
  else if (e < 11534336u) { s = Wv; off = e - 10485760u; }
  else                    { s = Wp; off = e - 11534336u; }
  const float4* p = reinterpret_cast<const float4*>(s + off);
  float4 a = p[0], b = p[1];
  int4 r;
  r.x = (int)cvtpk(a.x, a.y); r.y = (int)cvtpk(a.z, a.w);
  r.z = (int)cvtpk(b.x, b.y); r.w = (int)cvtpk(b.z, b.w);
  *reinterpret_cast<int4*>(o + e) = r;
}

// ---------------------------------------------------------------------------
// Fused QKV GEMM (m97 structure) + fused per-head LayerNorm epilogue.
// XCD-aware tile swizzle. 3 z-slices.
// ---------------------------------------------------------------------------
__global__ __launch_bounds__(256, 4)
void gemm_qkv_bf(const unsigned short* __restrict__ xb,
                 const float* __restrict__ lg, const float* __restrict__ lb,
                 unsigned short* __restrict__ qb, unsigned short* __restrict__ kb,
                 unsigned short* __restrict__ vtb)
{
  __shared__ short As[128 * 64];
  __shared__ short Bs[128 * 64];
  const int tid = threadIdx.x;
  const int l = tid & 63, w = tid >> 6;
  const int wr = w >> 1, wc = w & 1;
  const int z = blockIdx.z;
  const unsigned short* A = (z == 0) ? xb : (xb + 4194304);
  const unsigned short* W = xb + 8388608 + (size_t)z * 1048576;
  const int id = blockIdx.x + (blockIdx.y << 3);
  const int tl = ((id & 7) << 5) | (id >> 3);
  const int bx = tl & 7, by = tl >> 3;
  const int brow = by * 128, bcol = bx * 128;

  const f32x4 zero = {0.f, 0.f, 0.f, 0.f};
  f32x4 acc[4][4];
#pragma unroll
  for (int mi = 0; mi < 4; ++mi)
#pragma unroll
    for (int ni = 0; ni < 4; ++ni) acc[mi][ni] = zero;

  const int srow = w * 32 + (l >> 3);
  const int scol = (l & 7) * 8;

  for (int kt = 0; kt < 16; ++kt) {
    const unsigned short* ga = A + (size_t)(brow + srow) * 1024 + kt * 64 + scol;
    const unsigned short* gb = W + (size_t)(bcol + srow) * 1024 + kt * 64 + scol;
#pragma unroll
    for (int i = 0; i < 4; ++i) {
      gl16(ga + (size_t)i * 8 * 1024, &As[(w * 32 + i * 8) * 64]);
      gl16(gb + (size_t)i * 8 * 1024, &Bs[(w * 32 + i * 8) * 64]);
    }
    __syncthreads();
#pragma unroll
    for (int kk = 0; kk < 2; ++kk) {
      const int k0 = kk * 32 + ((l >> 4) << 3);
      bf16x8 af[4], bfr[4];
#pragma unroll
      for (int mi = 0; mi < 4; ++mi)
        af[mi] = *reinterpret_cast<const bf16x8*>(
            &As[((wr << 6) + (mi << 4) + (l & 15)) * 64 + k0]);
#pragma unroll
      for (int ni = 0; ni < 4; ++ni)
        bfr[ni] = *reinterpret_cast<const bf16x8*>(
            &Bs[((wc << 6) + (ni << 4) + (l & 15)) * 64 + k0]);
#pragma unroll
      for (int mi = 0; mi < 4; ++mi)
#pragma unroll
        for (int ni = 0; ni < 4; ++ni)
          acc[mi][ni] = mfma16(af[mi], bfr[ni], acc[mi][ni]);
    }
    __syncthreads();
  }

  if (z < 2) {
    unsigned short* dst = (z == 0) ? qb : kb;
    const float scl = (z == 0) ? 0.18033688011112042f : 1.0f; // 0.125*log2(e)
    const int h = bx * 2 + wc;
    float gw4[4], bw4[4];
#pragma unroll
    for (int ni = 0; ni < 4; ++ni) {
      gw4[ni] = lg[ni * 16 + (l & 15)] * scl;
      bw4[ni] = lb[ni * 16 + (l & 15)] * scl;
    }
#pragma unroll
    for (int mi = 0; mi < 4; ++mi) {
      float ylo[4];
#pragma unroll
      for (int r = 0; r < 4; ++r) {
        float v0 = acc[mi][0][r], v1 = acc[mi][1][r];
        float v2 = acc[mi][2][r], v3 = acc[mi][3][r];
        float s  = (v0 + v1) + (v2 + v3);
        float s2 = (v0 * v0 + v1 * v1) + (v2 * v2 + v3 * v3);
#pragma unroll
        for (int off = 1; off < 16; off <<= 1) {
          s  += __shfl_xor(s, off);
          s2 += __shfl_xor(s2, off);
        }
        float mean = s * (1.f / 64.f);
        float var  = s2 * (1.f / 64.f) - mean * mean;
        float rstd = rsqrtf(var + 1e-5f);
        float y[4];
        y[0] = (v0 - mean) * rstd * gw4[0] + bw4[0];
        y[1] = (v1 - mean) * rstd * gw4[1] + bw4[1];
        y[2] = (v2 - mean) * rstd * gw4[2] + bw4[2];
        y[3] = (v3 - mean) * rstd * gw4[3] + bw4[3];
        if (!(r & 1)) {
          ylo[0] = y[0]; ylo[1] = y[1]; ylo[2] = y[2]; ylo[3] = y[3];
        } else {
          int rowg0 = brow + (wr << 6) + (mi << 4) + ((l >> 4) << 2) + r - 1;
          int b = rowg0 >> 11, n = rowg0 & 2047;
          unsigned short* base =
              dst + (((size_t)(b * 16 + h) << 11) + n) * 64 + (l & 15);
#pragma unroll
          for (int ni = 0; ni < 4; ++ni) {
            unsigned u = cvtpk(ylo[ni], y[ni]);
            base[ni * 16]      = (unsigned short)(u & 0xffffu);
            base[ni * 16 + 64] = (unsigned short)(u >> 16);
          }
        }
      }
    }
  } else {
    const int bb = brow >> 11;
    const int nblk = brow & 2047;
#pragma unroll
    for (int mi = 0; mi < 4; ++mi)
#pragma unroll
      for (int ni = 0; ni < 4; ++ni) {
        int n0 = nblk + (wr << 6) + (mi << 4) + ((l >> 4) << 2);
        int colg = bcol + (wc << 6) + (ni << 4) + (l & 15);
        int h = colg >> 6, d = colg & 63;
        unsigned u0 = cvtpk(acc[mi][ni][0], acc[mi][ni][1]);
        unsigned u1 = cvtpk(acc[mi][ni][2], acc[mi][ni][3]);
        int2 u; u.x = (int)u0; u.y = (int)u1;
        *reinterpret_cast<int2*>(
            &vtb[((size_t)(bb * 16 + h) * 64 + d) * 2048 + n0]) = u;
      }
  }
}

// ---------------------------------------------------------------------------
// Flash attention, SPLIT-KV x2, 64-q-rows-per-wave (round-18 champion body).
// K/V staged via global_load_lds (linear LDS dest + INVERSE-swizzled global
// source); XOR-swizzled reads; static exp2 softmax; ones-MFMA row-sum.
// ---------------------------------------------------------------------------
__global__ __launch_bounds__(128, 2)
void attn_fwd(const unsigned short* __restrict__ Q,
              const unsigned short* __restrict__ K,
              const unsigned short* __restrict__ Vt,
              unsigned short* __restrict__ pnum,
              float* __restrict__ plsum)
{
  __shared__ short Ks[2][64 * 64];
  __shared__ short Vs[2][64 * 64];
  const int tid = threadIdx.x, w = tid >> 6, l = tid & 63;
  const int lo5 = l & 31, hi = l >> 5;
  const int bh = blockIdx.y;
  const int half = blockIdx.z;
  const int tbase = half * 16;
  const int qbase = blockIdx.x * 128 + w * 64;
  const unsigned short* Qg = Q + ((size_t)bh * 2048 + qbase) * 64;
  const unsigned short* Kg = K + (size_t)bh * 2048 * 64;
  const unsigned short* Vg = Vt + (size_t)bh * 64 * 2048;

  bf16x8 qfA[4], qfB[4];
#pragma unroll
  for (int ks = 0; ks < 4; ++ks) {
    qfA[ks] = *reinterpret_cast<const bf16x8*>(Qg + lo5 * 64 + ks * 16 + hi * 8);
    qfB[ks] = *reinterpret_cast<const bf16x8*>(Qg + (32 + lo5) * 64 + ks * 16 + hi * 8);
  }
  const bf16x8 ones = mk8(0x3F803F80u, 0x3F803F80u, 0x3F803F80u, 0x3F803F80u);

  f32x16 oc0a = zero16(), oc1a = zero16(), lsa = zero16();
  f32x16 oc0b = zero16(), oc1b = zero16(), lsb = zero16();

  // staging geometry: thread covers rows srow+16g (g=0..3), 16B slot tid&7.
  // gl16: LDS dest linear (wave-uniform base + lane*16); global source column
  // carries the INVERSE swizzle (XOR is an involution).
  const int srow = tid >> 3;                          // 0..15
  const int scs = (((tid & 7) ^ (srow & 7)) * 8);     // pre-swizzled src col

  const unsigned short* kp = Kg + (size_t)tbase * 4096 + srow * 64 + scs;
  const unsigned short* vp = Vg + (size_t)tbase * 64 + (size_t)srow * 2048 + scs;
  short* kd0 = &Ks[0][w * 512]; short* kd1 = &Ks[1][w * 512];
  short* vd0 = &Vs[0][w * 512]; short* vd1 = &Vs[1][w * 512];

#define STAGEKV(KD, VD)                                                        \
  gl16(kp,         (KD));                                                      \
  gl16(kp + 1024,  (KD) + 1024);                                               \
  gl16(kp + 2048,  (KD) + 2048);                                               \
  gl16(kp + 3072,  (KD) + 3072);                                               \
  gl16(vp,         (VD));                                                      \
  gl16(vp + 32768, (VD) + 1024);                                               \
  gl16(vp + 65536, (VD) + 2048);                                               \
  gl16(vp + 98304, (VD) + 3072);                                               \
  kp += 4096; vp += 64

  STAGEKV(kd0, vd0);          // prologue: tile tbase -> buffer 0
  __syncthreads();

  for (int it = 0; it < 16; ++it) {
    const int cur = it & 1;
    const short* Kc = Ks[cur];
    const short* Vc = Vs[cur];

    if (it < 15) {            // stage next tile into the other buffer (async)
      if (cur == 0) { STAGEKV(kd1, vd1); }
      else          { STAGEKV(kd0, vd0); }
    }

    // QK^T (swapped): each K fragment feeds BOTH q-tiles
    f32x16 s0a = zero16(), s1a = zero16(), s0b = zero16(), s1b = zero16();
    __builtin_amdgcn_s_setprio(1);
#pragma unroll
    for (int ks = 0; ks < 4; ++ks) {
      const int colc = (16 * ks + 8 * hi) ^ ((lo5 & 7) << 3);
      bf16x8 k0 = *reinterpret_cast<const bf16x8*>(&Kc[(lo5 << 6) + colc]);
      bf16x8 k1 = *reinterpret_cast<const bf16x8*>(&Kc[((32 + lo5) << 6) + colc]);
      s0a = mfma32(k0, qfA[ks], s0a);
      s1a = mfma32(k1, qfA[ks], s1a);
      s0b = mfma32(k0, qfB[ks], s0b);
      s1b = mfma32(k1, qfB[ks], s1b);
    }
    __builtin_amdgcn_s_setprio(0);

    // static softmax + PV; V fragments shared by both q-tiles
    auto pvpair = [&](const f32x16& sa, const f32x16& sb, int jbase) {
      float pA[16], pB[16];
#pragma unroll
      for (int r = 0; r < 16; ++r) { pA[r] = EXP2(sa[r]); pB[r] = EXP2(sb[r]); }
#pragma unroll
      for (int f = 0; f < 2; ++f) {
        unsigned xA  = cvtpk(pA[8 * f + 0], pA[8 * f + 1]);
        unsigned zA  = cvtpk(pA[8 * f + 2], pA[8 * f + 3]);
        unsigned yA  = cvtpk(pA[8 * f + 4], pA[8 * f + 5]);
        unsigned wA  = cvtpk(pA[8 * f + 6], pA[8 * f + 7]);
        pl32swap(xA, yA);
        pl32swap(zA, wA);
        bf16x8 paA = mk8(xA, zA, yA, wA);
        unsigned xB  = cvtpk(pB[8 * f + 0], pB[8 * f + 1]);
        unsigned zB  = cvtpk(pB[8 * f + 2], pB[8 * f + 3]);
        unsigned yB  = cvtpk(pB[8 * f + 4], pB[8 * f + 5]);
        unsigned wB  = cvtpk(pB[8 * f + 6], pB[8 * f + 7]);
        pl32swap(xB, yB);
        pl32swap(zB, wB);
        bf16x8 paB = mk8(xB, zB, yB, wB);
        const int colc = (jbase + 16 * f + 8 * hi);
        bf16x8 v0 = *reinterpret_cast<const bf16x8*>(
            &Vc[(lo5 << 6) + (colc ^ ((lo5 & 7) << 3))]);
        bf16x8 v1 = *reinterpret_cast<const bf16x8*>(
            &Vc[((32 + lo5) << 6) + (colc ^ ((lo5 & 7) << 3))]);
        __builtin_amdgcn_s_setprio(1);
        oc0a = mfma32(paA, v0, oc0a);
        oc1a = mfma32(paA, v1, oc1a);
        lsa  = mfma32(paA, ones, lsa);
        oc0b = mfma32(paB, v0, oc0b);
        oc1b = mfma32(paB, v1, oc1b);
        lsb  = mfma32(paB, ones, lsb);
        __builtin_amdgcn_s_setprio(0);
      }
    };
    pvpair(s0a, s0b, 0);
    pvpair(s1a, s1b, 32);

    __syncthreads();   // drains this iter's gl16s (vmcnt 0 at barrier) + swap
  }
#undef STAGEKV

  // epilogue: write raw bf16 partial numerators + fp32 partial row-sums.
  unsigned short* Pn = pnum + ((size_t)(half * 32 + bh) * 2048 + qbase) * 64;
#pragma unroll
  for (int r = 0; r < 16; ++r) {
    int qrow = (r & 3) + 8 * (r >> 2) + 4 * hi;
    Pn[qrow * 64 + lo5]             = f2bf(oc0a[r]);
    Pn[qrow * 64 + 32 + lo5]        = f2bf(oc1a[r]);
    Pn[(32 + qrow) * 64 + lo5]      = f2bf(oc0b[r]);
    Pn[(32 + qrow) * 64 + 32 + lo5] = f2bf(oc1b[r]);
  }
  if (lo5 == 0) {
    float* Pl = plsum + (size_t)(half * 32 + bh) * 2048 + qbase;
#pragma unroll
    for (int r = 0; r < 16; ++r) {
      int qrow = (r & 3) + 8 * (r >> 2) + 4 * hi;
      Pl[qrow]      = lsa[r];
      Pl[32 + qrow] = lsb[r];
    }
  }
}

// ---------------------------------------------------------------------------
// Combine the two KV halves: out = (n0+n1)/(ls0+ls1), write obuf [B,N,H*64].
// ---------------------------------------------------------------------------
__global__ __launch_bounds__(256, 8)
void attn_combine(const unsigned short* __restrict__ pnum,
                  const float* __restrict__ plsum,
                  unsigned short* __restrict__ obuf)
{
  const int t = blockIdx.x * 256 + threadIdx.x;   // 0..524287
  const int bh = t >> 14;
  const int rem = t & 16383;
  const int q = rem >> 3, dblk = rem & 7;
  const size_t i0 = (((size_t)bh * 2048) + q) * 64 + dblk * 8;
  const size_t i1 = i0 + (size_t)32 * 2048 * 64;
  ushort4 a0 = *reinterpret_cast<const ushort4*>(pnum + i0);
  ushort4 a1 = *reinterpret_cast<const ushort4*>(pnum + i0 + 4);
  ushort4 b0 = *reinterpret_cast<const ushort4*>(pnum + i1);
  ushort4 b1 = *reinterpret_cast<const ushort4*>(pnum + i1 + 4);
  float ls = plsum[bh * 2048 + q] + plsum[65536 + bh * 2048 + q];
  float inv = 1.f / ls;
  ushort4 o0, o1;
  o0.x = f2bf((bf2f(a0.x) + bf2f(b0.x)) * inv);
  o0.y = f2bf((bf2f(a0.y) + bf2f(b0.y)) * inv);
  o0.z = f2bf((bf2f(a0.z) + bf2f(b0.z)) * inv);
  o0.w = f2bf((bf2f(a0.w) + bf2f(b0.w)) * inv);
  o1.x = f2bf((bf2f(a1.x) + bf2f(b1.x)) * inv);
  o1.y = f2bf((bf2f(a1.y) + bf2f(b1.y)) * inv);
  o1.z = f2bf((bf2f(a1.z) + bf2f(b1.z)) * inv);
  o1.w = f2bf((bf2f(a1.w) + bf2f(b1.w)) * inv);
  unsigned short* dst = obuf + ((size_t)(bh >> 4) * 2048 + q) * 1024 +
                        (bh & 15) * 64 + dblk * 8;
  *reinterpret_cast<ushort4*>(dst) = o0;
  *reinterpret_cast<ushort4*>(dst + 4) = o1;
}

// ---------------------------------------------------------------------------
// Output projection (m97 structure): out = Ocat @ Wp^T + bp, fp32 out.
// XCD-aware tile swizzle.
// ---------------------------------------------------------------------------
__global__ __launch_bounds__(256, 4)
void gemm_out_bf(const unsigned short* __restrict__ ob,
                 const unsigned short* __restrict__ wpb,
                 const float* __restrict__ bp, float* __restrict__ out)
{
  __shared__ short As[128 * 64];
  __shared__ short Bs[128 * 64];
  const int tid = threadIdx.x;
  const int l = tid & 63, w = tid >> 6;
  const int wr = w >> 1, wc = w & 1;
  const int id = blockIdx.x + (blockIdx.y << 3);
  const int tl = ((id & 7) << 5) | (id >> 3);
  const int brow = (tl >> 3) * 128, bcol = (tl & 7) * 128;

  const f32x4 zero = {0.f, 0.f, 0.f, 0.f};
  f32x4 acc[4][4];
#pragma unroll
  for (int mi = 0; mi < 4; ++mi)
#pragma unroll
    for (int ni = 0; ni < 4; ++ni) acc[mi][ni] = zero;

  const int srow = w * 32 + (l >> 3);
  const int scol = (l & 7) * 8;

  for (int kt = 0; kt < 16; ++kt) {
    const unsigned short* ga = ob + (size_t)(brow + srow) * 1024 + kt * 64 + scol;
    const unsigned short* gb = wpb + (size_t)(bcol + srow) * 1024 + kt * 64 + scol;
#pragma unroll
    for (int i = 0; i < 4; ++i) {
      gl16(ga + (size_t)i * 8 * 1024, &As[(w * 32 + i * 8) * 64]);
      gl16(gb + (size_t)i * 8 * 1024, &Bs[(w * 32 + i * 8) * 64]);
    }
    __syncthreads();
#pragma unroll
    for (int kk = 0; kk < 2; ++kk) {
      const int k0 = kk * 32 + ((l >> 4) << 3);
      bf16x8 af[4], bfr[4];
#pragma unroll
      for (int mi = 0; mi < 4; ++mi)
        af[mi] = *reinterpret_cast<const bf16x8*>(
            &As[((wr << 6) + (mi << 4) + (l & 15)) * 64 + k0]);
#pragma unroll
      for (int ni = 0; ni < 4; ++ni)
        bfr[ni] = *reinterpret_cast<const bf16x8*>(
            &Bs[((wc << 6) + (ni << 4) + (l & 15)) * 64 + k0]);
#pragma unroll
      for (int mi = 0; mi < 4; ++mi)
#pragma unroll
        for (int ni = 0; ni < 4; ++ni)
          acc[mi][ni] = mfma16(af[mi], bfr[ni], acc[mi][ni]);
    }
    __syncthreads();
  }

  float bias[4];
#pragma unroll
  for (int ni = 0; ni < 4; ++ni)
    bias[ni] = bp[bcol + (wc << 6) + (ni << 4) + (l & 15)];
#pragma unroll
  for (int mi = 0; mi < 4; ++mi)
#pragma unroll
    for (int ni = 0; ni < 4; ++ni)
#pragma unroll
      for (int r = 0; r < 4; ++r) {
        int rowg = brow + (wr << 6) + (mi << 4) + ((l >> 4) << 2) + r;
        int colg = bcol + (wc << 6) + (ni << 4) + (l & 15);
        out[(size_t)rowg * 1024 + colg] = acc[mi][ni][r] + bias[ni];
      }
}

// ---------------------------------------------------------------------------
extern "C" void kernel_launch(void* const* d_in, const int* in_sizes, int n_in,
                              void* d_out, int out_size, void* d_ws, size_t ws_size,
                              hipStream_t stream)
{
  const float* x1 = (const float*)d_in[0];
  const float* x2 = (const float*)d_in[1];
  const float* Wq = (const float*)d_in[2];
  const float* Wk = (const float*)d_in[3];
  const float* Wv = (const float*)d_in[4];
  const float* Wp = (const float*)d_in[5];
  const float* bp = (const float*)d_in[6];
  const float* lg = (const float*)d_in[7];
  const float* lb = (const float*)d_in[8];

  char* wsb = (char*)d_ws;
  unsigned short* xb   = (unsigned short*)wsb;              // 24 MiB (12M ushort)
  unsigned short* qb   = (unsigned short*)(wsb + 25165824); // 8 MiB
  unsigned short* kb   = qb + 4194304;                      // 8 MiB
  unsigned short* vtb  = kb + 4194304;                      // 8 MiB (V^T)
  unsigned short* obuf = vtb + 4194304;                     // 8 MiB
  unsigned short* pnum = obuf + 4194304;                    // 16 MiB (2 halves)
  float* plsum = (float*)(wsb + 75497472);                  // 512 KiB
  float* out = (float*)d_out;

  conv_bf16<<<6144, 256, 0, stream>>>(x1, x2, Wq, Wk, Wv, Wp, xb);
  gemm_qkv_bf<<<dim3(8, 32, 3), 256, 0, stream>>>(xb, lg, lb, qb, kb, vtb);
  attn_fwd<<<dim3(16, 32, 2), 128, 0, stream>>>(qb, kb, vtb, pnum, plsum);
  attn_combine<<<2048, 256, 0, stream>>>(pnum, plsum, obuf);
  gemm_out_bf<<<dim3(8, 32), 256, 0, stream>>>(obuf,
      xb + 11534336, bp, out);
}